// Round 5
// baseline (480.642 us; speedup 1.0000x reference)
//
#include <hip/hip_runtime.h>

typedef unsigned short u16;
typedef unsigned int   u32;
typedef __attribute__((ext_vector_type(8))) short short8;
typedef __attribute__((ext_vector_type(4))) float floatx4;

// ---------- helpers ----------
__device__ inline u16 f2bf(float x) {
  union { float f; unsigned u; } v; v.f = x;
  unsigned r = v.u + 0x7FFFu + ((v.u >> 16) & 1u);   // RNE
  return (u16)(r >> 16);
}
__device__ inline float bf2f(short s) {
  union { u32 u; float f; } v; v.u = ((u32)(u16)s) << 16; return v.f;
}
__device__ inline short8 ld8(const u16* p) {
  return *reinterpret_cast<const short8*>(p);
}
// async global->LDS DMA, 16B per lane; lds dest = wave-uniform base + lane*16
__device__ inline void async_ld16(const u16* g, u16* l) {
  unsigned loff = (unsigned)(unsigned long long)(void*)l;
  __builtin_amdgcn_global_load_lds(reinterpret_cast<const unsigned*>(g),
      reinterpret_cast<__attribute__((address_space(3))) unsigned*>(loff), 16, 0, 0);
}

// ---------- weight casts fp32 -> bf16 (both weights, one launch) ----------
__global__ __launch_bounds__(256) void cast_both(const float* __restrict__ s1,
                                                 u16* __restrict__ d1,
                                                 const float* __restrict__ s2,
                                                 u16* __restrict__ d2) {
  const float* src; u16* dst; int i;
  if (blockIdx.x < 768) { src = s1; dst = d1; i = blockIdx.x * 256 + threadIdx.x; }
  else                  { src = s2; dst = d2; i = (blockIdx.x - 768) * 256 + threadIdx.x; }
  float4 v = reinterpret_cast<const float4*>(src)[i];
  union { u16 u[4]; float2 f; } w;
  w.u[0] = f2bf(v.x); w.u[1] = f2bf(v.y); w.u[2] = f2bf(v.z); w.u[3] = f2bf(v.w);
  reinterpret_cast<float2*>(dst)[i] = w.f;
}

// ---------- GroupNorm 1: x (B,C,T) fp32 -> xn (B,T,C) bf16 ----------
__global__ __launch_bounds__(1024) void gn_ct(const float* __restrict__ x,
                                              const float* __restrict__ gamma,
                                              const float* __restrict__ beta,
                                              u16* __restrict__ xn) {
  int b = blockIdx.x >> 5, g = blockIdx.x & 31;
  const float* base = x + ((long)b * 512 + g * 16) * 2048;
  float s = 0.f, ss = 0.f;
  for (int i = threadIdx.x; i < 8192; i += 1024) {
    float4 v = reinterpret_cast<const float4*>(base)[i];
    s  += v.x + v.y + v.z + v.w;
    ss += v.x * v.x + v.y * v.y + v.z * v.z + v.w * v.w;
  }
  #pragma unroll
  for (int d = 1; d < 64; d <<= 1) { s += __shfl_xor(s, d); ss += __shfl_xor(ss, d); }
  __shared__ float red[32];
  int wave = threadIdx.x >> 6, lane = threadIdx.x & 63;
  if (lane == 0) { red[wave] = s; red[wave + 16] = ss; }
  __syncthreads();
  s = 0.f; ss = 0.f;
  #pragma unroll
  for (int w = 0; w < 16; w++) { s += red[w]; ss += red[w + 16]; }
  float mean = s * (1.f / 32768.f);
  float var  = ss * (1.f / 32768.f) - mean * mean;
  float rstd = rsqrtf(var + 1e-5f);
  float ga[16], be[16];
  #pragma unroll
  for (int c = 0; c < 16; c++) {
    float gm = gamma[g * 16 + c];
    ga[c] = gm * rstd;
    be[c] = beta[g * 16 + c] - mean * rstd * gm;
  }
  u16* ob = xn + (long)b * 2048 * 512 + g * 16;
  for (int t = threadIdx.x; t < 2048; t += 1024) {
    union { u16 u[8]; float4 f; } w0, w1;
    #pragma unroll
    for (int c = 0; c < 8; c++)  w0.u[c]     = f2bf(base[c * 2048 + t] * ga[c] + be[c]);
    #pragma unroll
    for (int c = 8; c < 16; c++) w1.u[c - 8] = f2bf(base[c * 2048 + t] * ga[c] + be[c]);
    u16* dst = ob + (long)t * 512;
    *reinterpret_cast<float4*>(dst)     = w0.f;
    *reinterpret_cast<float4*>(dst + 8) = w1.f;
  }
}

// ---------- GroupNorm 2: a (B,T,C) bf16 -> hn (B,T,C) bf16 ----------
__global__ __launch_bounds__(1024) void gn_tc(const u16* __restrict__ a,
                                              const float* __restrict__ gamma,
                                              const float* __restrict__ beta,
                                              u16* __restrict__ hn) {
  int b = blockIdx.x >> 5, g = blockIdx.x & 31;
  const u16* base = a + (long)b * 2048 * 512 + g * 16;
  float s = 0.f, ss = 0.f;
  for (int t = threadIdx.x; t < 2048; t += 1024) {
    const u16* p = base + (long)t * 512;
    short8 v0 = ld8(p), v1 = ld8(p + 8);
    #pragma unroll
    for (int j = 0; j < 8; j++) {
      float f0 = bf2f(v0[j]), f1 = bf2f(v1[j]);
      s += f0 + f1; ss += f0 * f0 + f1 * f1;
    }
  }
  #pragma unroll
  for (int d = 1; d < 64; d <<= 1) { s += __shfl_xor(s, d); ss += __shfl_xor(ss, d); }
  __shared__ float red[32];
  int wave = threadIdx.x >> 6, lane = threadIdx.x & 63;
  if (lane == 0) { red[wave] = s; red[wave + 16] = ss; }
  __syncthreads();
  s = 0.f; ss = 0.f;
  #pragma unroll
  for (int w = 0; w < 16; w++) { s += red[w]; ss += red[w + 16]; }
  float mean = s * (1.f / 32768.f);
  float var  = ss * (1.f / 32768.f) - mean * mean;
  float rstd = rsqrtf(var + 1e-5f);
  float ga[16], be[16];
  #pragma unroll
  for (int c = 0; c < 16; c++) {
    float gm = gamma[g * 16 + c];
    ga[c] = gm * rstd;
    be[c] = beta[g * 16 + c] - mean * rstd * gm;
  }
  u16* ob = hn + (long)b * 2048 * 512 + g * 16;
  for (int t = threadIdx.x; t < 2048; t += 1024) {
    const u16* p = base + (long)t * 512;
    short8 v0 = ld8(p), v1 = ld8(p + 8);
    union { u16 u[8]; float4 f; } w0, w1;
    #pragma unroll
    for (int c = 0; c < 8; c++)  w0.u[c] = f2bf(bf2f(v0[c]) * ga[c] + be[c]);
    #pragma unroll
    for (int c = 0; c < 8; c++)  w1.u[c] = f2bf(bf2f(v1[c]) * ga[c + 8] + be[c + 8]);
    u16* dst = ob + (long)t * 512;
    *reinterpret_cast<float4*>(dst)     = w0.f;
    *reinterpret_cast<float4*>(dst + 8) = w1.f;
  }
}

// ---------- unified TN GEMM: D[m][n] = sum_k A[m][k] * Bt[n][k] ----------
// Double-buffered async K-loop: one barrier/iter, prefetch k+1 during compute k.
// QKV==1: out = qkv bf16 (b,t,1536), q-channels pre-scaled by 0.125*log2e,
//         v-channels routed to Vt (B,NH,64,T) as packed 8B stores.
// QKV==0: out = fp32 (b, m, N) with bias[m] + residual.
template<int QKV>
__global__ __launch_bounds__(256) void gemm_tn(
    const u16* __restrict__ A, long abst,
    const u16* __restrict__ Bt, long bbst,
    const float* __restrict__ bias,
    const float* __restrict__ resid, long rbst,
    void* __restrict__ outp, long obst,
    u16* __restrict__ vtp, int K) {
  __shared__ __align__(16) u16 As[2][128 * 32];
  __shared__ __align__(16) u16 Bs[2][128 * 32];
  const int tid = threadIdx.x;
  const int m0 = blockIdx.y * 128, n0 = blockIdx.x * 128;
  const int N = gridDim.x * 128;
  const long bz = blockIdx.z;
  const u16* Ab = A + bz * abst + (long)m0 * K;
  const u16* Bb = Bt + bz * bbst + (long)n0 * K;
  const int lane = tid & 63, wave = tid >> 6;
  const int wm = (wave & 1) * 64, wn = (wave >> 1) * 64;
  const int l15 = lane & 15, quad = lane >> 4;
  const u16* ag[2]; const u16* bg[2];
  const int ldso = wave * 512;
  #pragma unroll
  for (int half = 0; half < 2; half++) {
    int r = half * 64 + (tid >> 2);
    ag[half] = Ab + (long)r * K + (tid & 3) * 8;
    bg[half] = Bb + (long)r * K + (tid & 3) * 8;
  }

  floatx4 acc[4][4];
  #pragma unroll
  for (int i = 0; i < 4; i++)
    #pragma unroll
    for (int j = 0; j < 4; j++) acc[i][j] = (floatx4){0.f, 0.f, 0.f, 0.f};

  // prefetch k-tile 0 into buffer 0
  #pragma unroll
  for (int half = 0; half < 2; half++) {
    async_ld16(ag[half], &As[0][half * 2048 + ldso]);
    async_ld16(bg[half], &Bs[0][half * 2048 + ldso]);
  }
  const int nk = K >> 5;
  for (int ki = 0; ki < nk; ki++) {
    __syncthreads();                       // publishes buffer ki&1
    if (ki + 1 < nk) {                     // prefetch next tile into other buffer
      int k1 = (ki + 1) << 5, bsel = (ki + 1) & 1;
      #pragma unroll
      for (int half = 0; half < 2; half++) {
        async_ld16(ag[half] + k1, &As[bsel][half * 2048 + ldso]);
        async_ld16(bg[half] + k1, &Bs[bsel][half * 2048 + ldso]);
      }
    }
    const u16* as = As[ki & 1]; const u16* bs = Bs[ki & 1];
    short8 af[4], bfr[4];
    #pragma unroll
    for (int i = 0; i < 4; i++) af[i]  = ld8(&as[(wm + i * 16 + l15) * 32 + quad * 8]);
    #pragma unroll
    for (int i = 0; i < 4; i++) bfr[i] = ld8(&bs[(wn + i * 16 + l15) * 32 + quad * 8]);
    #pragma unroll
    for (int mi = 0; mi < 4; mi++)
      #pragma unroll
      for (int ni = 0; ni < 4; ni++)
        acc[mi][ni] = __builtin_amdgcn_mfma_f32_16x16x32_bf16(af[mi], bfr[ni], acc[mi][ni], 0, 0, 0);
  }

  if (QKV) {
    u16* D  = (u16*)outp + bz * obst;
    u16* VT = vtp + bz * (8L * 64 * 2048);
    #pragma unroll
    for (int ni = 0; ni < 4; ni++) {
      int nb = n0 + wn + ni * 16;              // tile base (uniform)
      int region = (nb >> 6) % 3;              // 0=q, 1=k, 2=v
      int n = nb + l15;
      float bn = bias[n];
      if (region == 2) {
        int hh = n / 192, c = (n % 192) - 128;
        u16* vrow = VT + ((long)hh * 64 + c) * 2048 + m0 + wm;
        #pragma unroll
        for (int mi = 0; mi < 4; mi++) {
          union { u16 u[4]; float2 f; } pk;
          #pragma unroll
          for (int r = 0; r < 4; r++) pk.u[r] = f2bf(acc[mi][ni][r] + bn);
          *reinterpret_cast<float2*>(vrow + mi * 16 + quad * 4) = pk.f;
        }
      } else {
        float sc = (region == 0) ? 0.180336880f : 1.f;   // 0.125 * log2(e)
        #pragma unroll
        for (int mi = 0; mi < 4; mi++)
          #pragma unroll
          for (int r = 0; r < 4; r++) {
            int m = m0 + wm + mi * 16 + quad * 4 + r;
            D[(long)m * 1536 + n] = f2bf((acc[mi][ni][r] + bn) * sc);
          }
      }
    }
  } else {
    float* D = (float*)outp + bz * obst;
    const float* R = resid + bz * rbst;
    #pragma unroll
    for (int mi = 0; mi < 4; mi++)
      #pragma unroll
      for (int r = 0; r < 4; r++) {
        int m = m0 + wm + mi * 16 + quad * 4 + r;
        float bm = bias[m];
        #pragma unroll
        for (int ni = 0; ni < 4; ni++) {
          int n = n0 + wn + ni * 16 + l15;
          long idx = (long)m * N + n;
          D[idx] = acc[mi][ni][r] + bm + R[idx];
        }
      }
  }
}

// ---------- flash attention (S^T formulation, async dbuf K/V, no-max softmax) ----------
// qkv: (B,T,1536) bf16, Q pre-scaled by 0.125*log2e; vt: (B,NH,64,T) bf16.
// Scores s = (q.k)/8 bounded -> p = exp2(s*log2e) without max-subtraction;
// l = sum p via ones-MFMA. P round-trips LDS in two 32-tk halves (4KB/wave)
// so total LDS = 48KB -> 3 blocks/CU.
__global__ __launch_bounds__(256, 3) void attn(const u16* __restrict__ qkv,
                                               const u16* __restrict__ vt,
                                               u16* __restrict__ aout) {
  __shared__ __align__(16) u16 Ps[4][64 * 32];   // 16KB: per-wave 64 tq x 32 tk half
  __shared__ __align__(16) u16 Ks[2][64 * 64];   // 2x8KB
  __shared__ __align__(16) u16 Vs[2][64 * 64];   // 2x8KB
  const int tid = threadIdx.x, lane = tid & 63, wave = tid >> 6;
  const int l15 = lane & 15, quad = lane >> 4;
  const int sw = l15 & 7;                        // K/V row-swizzle key
  const int sw2 = l15 & 3;                       // P row-swizzle key (4 granules)
  const int b = blockIdx.y >> 3, h = blockIdx.y & 7;
  const int t0 = blockIdx.x * 256;
  const u16* qbase = qkv + (long)b * 2048 * 1536 + h * 192;
  const u16* vbase = vt + (long)(b * 8 + h) * 64 * 2048;
  u16* PsW = &Ps[wave][0];

  // Q fragments straight from global (A-layout: 16B/lane)
  short8 qf[4][2];
  #pragma unroll
  for (int tqi = 0; tqi < 4; tqi++)
    #pragma unroll
    for (int ks = 0; ks < 2; ks++)
      qf[tqi][ks] = ld8(qbase + (long)(t0 + wave * 64 + tqi * 16 + l15) * 1536 + ks * 32 + quad * 8);

  // ones A-fragment for l-sum MFMA (bf16 1.0 = 0x3F80)
  short8 ones;
  #pragma unroll
  for (int j = 0; j < 8; j++) ones[j] = (short)0x3F80;

  // staging source pointers: lane covers phys chunk p, reads logical chunk c = (p&7)^(row&7)
  const u16* kg[2]; const u16* vg[2]; int ldso[2];
  #pragma unroll
  for (int half = 0; half < 2; half++) {
    int p = half * 256 + wave * 64 + lane;
    int row = p >> 3, c = (p & 7) ^ (row & 7);
    kg[half] = qbase + (long)row * 1536 + 64 + c * 8;
    vg[half] = vbase + (long)row * 2048 + c * 8;
    ldso[half] = (half * 256 + wave * 64) * 8;
  }
  #pragma unroll
  for (int half = 0; half < 2; half++) {
    async_ld16(kg[half], &Ks[0][ldso[half]]);
    async_ld16(vg[half], &Vs[0][ldso[half]]);
  }

  floatx4 accO[4][4];   // [ci][tqi]: row=c, col=tq
  floatx4 lacc[4];      // [tqi]
  #pragma unroll
  for (int ci = 0; ci < 4; ci++)
    #pragma unroll
    for (int tqi = 0; tqi < 4; tqi++) accO[ci][tqi] = (floatx4){0.f, 0.f, 0.f, 0.f};
  #pragma unroll
  for (int tqi = 0; tqi < 4; tqi++) lacc[tqi] = (floatx4){0.f, 0.f, 0.f, 0.f};

  for (int it = 0; it < 32; it++) {
    const u16* kb = Ks[it & 1];
    const u16* vb = Vs[it & 1];
    __syncthreads();                     // publishes tile it; frees buffer it^1
    if (it < 31) {                       // prefetch tile it+1
      int s1 = (it + 1) * 64;
      u16* kn = Ks[(it & 1) ^ 1];
      u16* vn = Vs[(it & 1) ^ 1];
      #pragma unroll
      for (int half = 0; half < 2; half++) {
        async_ld16(kg[half] + (long)s1 * 1536, &kn[ldso[half]]);
        async_ld16(vg[half] + s1,              &vn[ldso[half]]);
      }
    }

    // S^T[tk][tq] = sum_c K[tk][c] * Q[tq][c]
    floatx4 sacc[4][4];   // [tki][tqi]
    #pragma unroll
    for (int i = 0; i < 4; i++)
      #pragma unroll
      for (int j = 0; j < 4; j++) sacc[i][j] = (floatx4){0.f, 0.f, 0.f, 0.f};
    #pragma unroll
    for (int ks = 0; ks < 2; ks++) {
      short8 kf[4];
      #pragma unroll
      for (int tki = 0; tki < 4; tki++)
        kf[tki] = ld8(&kb[((tki * 16 + l15) << 6) + (((ks * 4 + quad) ^ sw) << 3)]);
      #pragma unroll
      for (int tki = 0; tki < 4; tki++)
        #pragma unroll
        for (int tqi = 0; tqi < 4; tqi++)
          sacc[tki][tqi] = __builtin_amdgcn_mfma_f32_16x16x32_bf16(kf[tki], qf[tqi][ks], sacc[tki][tqi], 0, 0, 0);
    }

    // Two 32-tk halves: exp2+pack+write P half, then PV/l MFMAs on that half.
    #pragma unroll
    for (int ks = 0; ks < 2; ks++) {
      #pragma unroll
      for (int tqi = 0; tqi < 4; tqi++) {
        int prow = (tqi * 16 + l15) << 5;          // 32 u16 per row
        #pragma unroll
        for (int th = 0; th < 2; th++) {
          int tki = ks * 2 + th;
          float p0 = __builtin_amdgcn_exp2f(sacc[tki][tqi][0]);
          float p1 = __builtin_amdgcn_exp2f(sacc[tki][tqi][1]);
          float p2 = __builtin_amdgcn_exp2f(sacc[tki][tqi][2]);
          float p3 = __builtin_amdgcn_exp2f(sacc[tki][tqi][3]);
          union { u32 u[2]; float2 f; } pk;
          pk.u[0] = __builtin_amdgcn_perm(__float_as_uint(p1), __float_as_uint(p0), 0x07060302);
          pk.u[1] = __builtin_amdgcn_perm(__float_as_uint(p3), __float_as_uint(p2), 0x07060302);
          int c4 = th * 2 + (quad >> 1);           // 16B granule within row
          *reinterpret_cast<float2*>(
              &PsW[prow + (((c4 ^ sw2) << 3) | ((quad & 1) << 2))]) = pk.f;
        }
      }
      short8 vf[4], pf[4];
      #pragma unroll
      for (int ci = 0; ci < 4; ci++)
        vf[ci] = ld8(&vb[((ci * 16 + l15) << 6) + (((ks * 4 + quad) ^ sw) << 3)]);
      #pragma unroll
      for (int tqi = 0; tqi < 4; tqi++)
        pf[tqi] = ld8(&PsW[((tqi * 16 + l15) << 5) + ((quad ^ sw2) << 3)]);
      #pragma unroll
      for (int tqi = 0; tqi < 4; tqi++)
        lacc[tqi] = __builtin_amdgcn_mfma_f32_16x16x32_bf16(ones, pf[tqi], lacc[tqi], 0, 0, 0);
      #pragma unroll
      for (int ci = 0; ci < 4; ci++)
        #pragma unroll
        for (int tqi = 0; tqi < 4; tqi++)
          accO[ci][tqi] = __builtin_amdgcn_mfma_f32_16x16x32_bf16(vf[ci], pf[tqi], accO[ci][tqi], 0, 0, 0);
    }
  }

  // epilogue: normalize, write a (B,T,C) bf16; lane holds 4 consecutive c
  u16* ob = aout + ((long)b * 2048 + t0 + wave * 64) * 512 + h * 64;
  #pragma unroll
  for (int tqi = 0; tqi < 4; tqi++) {
    float invl = 1.f / lacc[tqi][0];
    #pragma unroll
    for (int ci = 0; ci < 4; ci++) {
      union { u16 u[4]; float2 f; } pk;
      #pragma unroll
      for (int r = 0; r < 4; r++) pk.u[r] = f2bf(accO[ci][tqi][r] * invl);
      *reinterpret_cast<float2*>(ob + (long)(tqi * 16 + l15) * 512 + ci * 16 + quad * 4) = pk.f;
    }
  }
}

// ---------- launch ----------
extern "C" void kernel_launch(void* const* d_in, const int* in_sizes, int n_in,
                              void* d_out, int out_size, void* d_ws, size_t ws_size,
                              hipStream_t stream) {
  const float* x   = (const float*)d_in[0];
  const float* g1  = (const float*)d_in[1];
  const float* be1 = (const float*)d_in[2];
  const float* wq  = (const float*)d_in[3];
  const float* bq  = (const float*)d_in[4];
  const float* g2  = (const float*)d_in[5];
  const float* be2 = (const float*)d_in[6];
  const float* wp  = (const float*)d_in[7];
  const float* bp  = (const float*)d_in[8];

  char* ws = (char*)d_ws;
  u16*   xn   = (u16*)ws;                        // 16.8 MB, dead after gemm1
  u16*   a    = (u16*)ws;                        // bf16 attn out, alias xn (disjoint lifetime)
  u16*   qkvb = (u16*)(ws + 33554432);           // 50.3 MB (q/k live, v-holes unused)
  u16*   hn   = (u16*)(ws + 83886080);           // 16.8 MB, gn2 -> gemm2
  u16*   vtb  = hn;                              // alias: Vt lifetime gemm1 -> attn
  u16*   wqb  = (u16*)(ws + 100663296);          // 1.6 MB
  u16*   wpb  = (u16*)(ws + 102236160);          // 0.5 MB

  cast_both<<<1024, 256, 0, stream>>>(wq, wqb, wp, wpb);
  gn_ct<<<256, 1024, 0, stream>>>(x, g1, be1, xn);
  // qkv[b][t][o] = sum_c xn[b][t][c] * Wq[o][c] + bq[o]  (+ q-scale, v->Vt)
  gemm_tn<1><<<dim3(12, 16, 8), 256, 0, stream>>>(
      xn, (long)2048 * 512, wqb, 0, bq, nullptr, 0, qkvb, (long)2048 * 1536, vtb, 512);
  attn<<<dim3(8, 64), 256, 0, stream>>>(qkvb, vtb, a);
  gn_tc<<<256, 1024, 0, stream>>>(a, g2, be2, hn);
  // out[b][o][t] = x[b][o][t] + bp[o] + sum_c Wp[o][c] * hn[b][t][c]
  gemm_tn<0><<<dim3(16, 4, 8), 256, 0, stream>>>(
      wpb, 0, hn, (long)2048 * 512, bp, x, (long)512 * 2048, d_out, (long)512 * 2048, nullptr, 512);
}

// Round 6
// 288.013 us; speedup vs baseline: 1.6688x; 1.6688x over previous
//
#include <hip/hip_runtime.h>

typedef unsigned short u16;
typedef unsigned int   u32;
typedef __attribute__((ext_vector_type(8))) short short8;
typedef __attribute__((ext_vector_type(4))) float floatx4;

// ---------- helpers ----------
__device__ inline u16 f2bf(float x) {
  union { float f; unsigned u; } v; v.f = x;
  unsigned r = v.u + 0x7FFFu + ((v.u >> 16) & 1u);   // RNE
  return (u16)(r >> 16);
}
__device__ inline float bf2f(short s) {
  union { u32 u; float f; } v; v.u = ((u32)(u16)s) << 16; return v.f;
}
__device__ inline short8 ld8(const u16* p) {
  return *reinterpret_cast<const short8*>(p);
}
// async global->LDS DMA, 16B per lane; lds dest = wave-uniform base + lane*16
__device__ inline void async_ld16(const u16* g, u16* l) {
  unsigned loff = (unsigned)(unsigned long long)(void*)l;
  __builtin_amdgcn_global_load_lds(reinterpret_cast<const unsigned*>(g),
      reinterpret_cast<__attribute__((address_space(3))) unsigned*>(loff), 16, 0, 0);
}

// ---------- weight casts fp32 -> bf16 (both weights, one launch) ----------
__global__ __launch_bounds__(256) void cast_both(const float* __restrict__ s1,
                                                 u16* __restrict__ d1,
                                                 const float* __restrict__ s2,
                                                 u16* __restrict__ d2) {
  const float* src; u16* dst; int i;
  if (blockIdx.x < 768) { src = s1; dst = d1; i = blockIdx.x * 256 + threadIdx.x; }
  else                  { src = s2; dst = d2; i = (blockIdx.x - 768) * 256 + threadIdx.x; }
  float4 v = reinterpret_cast<const float4*>(src)[i];
  union { u16 u[4]; float2 f; } w;
  w.u[0] = f2bf(v.x); w.u[1] = f2bf(v.y); w.u[2] = f2bf(v.z); w.u[3] = f2bf(v.w);
  reinterpret_cast<float2*>(dst)[i] = w.f;
}

// ---------- GroupNorm 1: x (B,C,T) fp32 -> xn (B,T,C) bf16 ----------
__global__ __launch_bounds__(1024) void gn_ct(const float* __restrict__ x,
                                              const float* __restrict__ gamma,
                                              const float* __restrict__ beta,
                                              u16* __restrict__ xn) {
  int b = blockIdx.x >> 5, g = blockIdx.x & 31;
  const float* base = x + ((long)b * 512 + g * 16) * 2048;
  float s = 0.f, ss = 0.f;
  for (int i = threadIdx.x; i < 8192; i += 1024) {
    float4 v = reinterpret_cast<const float4*>(base)[i];
    s  += v.x + v.y + v.z + v.w;
    ss += v.x * v.x + v.y * v.y + v.z * v.z + v.w * v.w;
  }
  #pragma unroll
  for (int d = 1; d < 64; d <<= 1) { s += __shfl_xor(s, d); ss += __shfl_xor(ss, d); }
  __shared__ float red[32];
  int wave = threadIdx.x >> 6, lane = threadIdx.x & 63;
  if (lane == 0) { red[wave] = s; red[wave + 16] = ss; }
  __syncthreads();
  s = 0.f; ss = 0.f;
  #pragma unroll
  for (int w = 0; w < 16; w++) { s += red[w]; ss += red[w + 16]; }
  float mean = s * (1.f / 32768.f);
  float var  = ss * (1.f / 32768.f) - mean * mean;
  float rstd = rsqrtf(var + 1e-5f);
  float ga[16], be[16];
  #pragma unroll
  for (int c = 0; c < 16; c++) {
    float gm = gamma[g * 16 + c];
    ga[c] = gm * rstd;
    be[c] = beta[g * 16 + c] - mean * rstd * gm;
  }
  u16* ob = xn + (long)b * 2048 * 512 + g * 16;
  for (int t = threadIdx.x; t < 2048; t += 1024) {
    union { u16 u[8]; float4 f; } w0, w1;
    #pragma unroll
    for (int c = 0; c < 8; c++)  w0.u[c]     = f2bf(base[c * 2048 + t] * ga[c] + be[c]);
    #pragma unroll
    for (int c = 8; c < 16; c++) w1.u[c - 8] = f2bf(base[c * 2048 + t] * ga[c] + be[c]);
    u16* dst = ob + (long)t * 512;
    *reinterpret_cast<float4*>(dst)     = w0.f;
    *reinterpret_cast<float4*>(dst + 8) = w1.f;
  }
}

// ---------- GroupNorm 2: a (B,T,C) bf16 -> hn (B,T,C) bf16 ----------
__global__ __launch_bounds__(1024) void gn_tc(const u16* __restrict__ a,
                                              const float* __restrict__ gamma,
                                              const float* __restrict__ beta,
                                              u16* __restrict__ hn) {
  int b = blockIdx.x >> 5, g = blockIdx.x & 31;
  const u16* base = a + (long)b * 2048 * 512 + g * 16;
  float s = 0.f, ss = 0.f;
  for (int t = threadIdx.x; t < 2048; t += 1024) {
    const u16* p = base + (long)t * 512;
    short8 v0 = ld8(p), v1 = ld8(p + 8);
    #pragma unroll
    for (int j = 0; j < 8; j++) {
      float f0 = bf2f(v0[j]), f1 = bf2f(v1[j]);
      s += f0 + f1; ss += f0 * f0 + f1 * f1;
    }
  }
  #pragma unroll
  for (int d = 1; d < 64; d <<= 1) { s += __shfl_xor(s, d); ss += __shfl_xor(ss, d); }
  __shared__ float red[32];
  int wave = threadIdx.x >> 6, lane = threadIdx.x & 63;
  if (lane == 0) { red[wave] = s; red[wave + 16] = ss; }
  __syncthreads();
  s = 0.f; ss = 0.f;
  #pragma unroll
  for (int w = 0; w < 16; w++) { s += red[w]; ss += red[w + 16]; }
  float mean = s * (1.f / 32768.f);
  float var  = ss * (1.f / 32768.f) - mean * mean;
  float rstd = rsqrtf(var + 1e-5f);
  float ga[16], be[16];
  #pragma unroll
  for (int c = 0; c < 16; c++) {
    float gm = gamma[g * 16 + c];
    ga[c] = gm * rstd;
    be[c] = beta[g * 16 + c] - mean * rstd * gm;
  }
  u16* ob = hn + (long)b * 2048 * 512 + g * 16;
  for (int t = threadIdx.x; t < 2048; t += 1024) {
    const u16* p = base + (long)t * 512;
    short8 v0 = ld8(p), v1 = ld8(p + 8);
    union { u16 u[8]; float4 f; } w0, w1;
    #pragma unroll
    for (int c = 0; c < 8; c++)  w0.u[c] = f2bf(bf2f(v0[c]) * ga[c] + be[c]);
    #pragma unroll
    for (int c = 0; c < 8; c++)  w1.u[c] = f2bf(bf2f(v1[c]) * ga[c + 8] + be[c + 8]);
    u16* dst = ob + (long)t * 512;
    *reinterpret_cast<float4*>(dst)     = w0.f;
    *reinterpret_cast<float4*>(dst + 8) = w1.f;
  }
}

// ---------- unified TN GEMM: D[m][n] = sum_k A[m][k] * Bt[n][k] ----------
// Double-buffered async K-loop: one barrier/iter, prefetch k+1 during compute k.
// QKV==1: out = qkv bf16 (b,t,1536), q-channels pre-scaled by 0.125*log2e,
//         v-channels routed to Vt (B,NH,64,T) as packed 8B stores.
// QKV==0: out = fp32 (b, m, N) with bias[m] + residual.
template<int QKV>
__global__ __launch_bounds__(256) void gemm_tn(
    const u16* __restrict__ A, long abst,
    const u16* __restrict__ Bt, long bbst,
    const float* __restrict__ bias,
    const float* __restrict__ resid, long rbst,
    void* __restrict__ outp, long obst,
    u16* __restrict__ vtp, int K) {
  __shared__ __align__(16) u16 As[2][128 * 32];
  __shared__ __align__(16) u16 Bs[2][128 * 32];
  const int tid = threadIdx.x;
  const int m0 = blockIdx.y * 128, n0 = blockIdx.x * 128;
  const int N = gridDim.x * 128;
  const long bz = blockIdx.z;
  const u16* Ab = A + bz * abst + (long)m0 * K;
  const u16* Bb = Bt + bz * bbst + (long)n0 * K;
  const int lane = tid & 63, wave = tid >> 6;
  const int wm = (wave & 1) * 64, wn = (wave >> 1) * 64;
  const int l15 = lane & 15, quad = lane >> 4;
  const u16* ag[2]; const u16* bg[2];
  const int ldso = wave * 512;
  #pragma unroll
  for (int half = 0; half < 2; half++) {
    int r = half * 64 + (tid >> 2);
    ag[half] = Ab + (long)r * K + (tid & 3) * 8;
    bg[half] = Bb + (long)r * K + (tid & 3) * 8;
  }

  floatx4 acc[4][4];
  #pragma unroll
  for (int i = 0; i < 4; i++)
    #pragma unroll
    for (int j = 0; j < 4; j++) acc[i][j] = (floatx4){0.f, 0.f, 0.f, 0.f};

  // prefetch k-tile 0 into buffer 0
  #pragma unroll
  for (int half = 0; half < 2; half++) {
    async_ld16(ag[half], &As[0][half * 2048 + ldso]);
    async_ld16(bg[half], &Bs[0][half * 2048 + ldso]);
  }
  const int nk = K >> 5;
  for (int ki = 0; ki < nk; ki++) {
    __syncthreads();                       // publishes buffer ki&1
    if (ki + 1 < nk) {                     // prefetch next tile into other buffer
      int k1 = (ki + 1) << 5, bsel = (ki + 1) & 1;
      #pragma unroll
      for (int half = 0; half < 2; half++) {
        async_ld16(ag[half] + k1, &As[bsel][half * 2048 + ldso]);
        async_ld16(bg[half] + k1, &Bs[bsel][half * 2048 + ldso]);
      }
    }
    const u16* as = As[ki & 1]; const u16* bs = Bs[ki & 1];
    short8 af[4], bfr[4];
    #pragma unroll
    for (int i = 0; i < 4; i++) af[i]  = ld8(&as[(wm + i * 16 + l15) * 32 + quad * 8]);
    #pragma unroll
    for (int i = 0; i < 4; i++) bfr[i] = ld8(&bs[(wn + i * 16 + l15) * 32 + quad * 8]);
    #pragma unroll
    for (int mi = 0; mi < 4; mi++)
      #pragma unroll
      for (int ni = 0; ni < 4; ni++)
        acc[mi][ni] = __builtin_amdgcn_mfma_f32_16x16x32_bf16(af[mi], bfr[ni], acc[mi][ni], 0, 0, 0);
  }

  if (QKV) {
    u16* D  = (u16*)outp + bz * obst;
    u16* VT = vtp + bz * (8L * 64 * 2048);
    #pragma unroll
    for (int ni = 0; ni < 4; ni++) {
      int nb = n0 + wn + ni * 16;              // tile base (uniform)
      int region = (nb >> 6) % 3;              // 0=q, 1=k, 2=v
      int n = nb + l15;
      float bn = bias[n];
      if (region == 2) {
        int hh = n / 192, c = (n % 192) - 128;
        u16* vrow = VT + ((long)hh * 64 + c) * 2048 + m0 + wm;
        #pragma unroll
        for (int mi = 0; mi < 4; mi++) {
          union { u16 u[4]; float2 f; } pk;
          #pragma unroll
          for (int r = 0; r < 4; r++) pk.u[r] = f2bf(acc[mi][ni][r] + bn);
          *reinterpret_cast<float2*>(vrow + mi * 16 + quad * 4) = pk.f;
        }
      } else {
        float sc = (region == 0) ? 0.180336880f : 1.f;   // 0.125 * log2(e)
        #pragma unroll
        for (int mi = 0; mi < 4; mi++)
          #pragma unroll
          for (int r = 0; r < 4; r++) {
            int m = m0 + wm + mi * 16 + quad * 4 + r;
            D[(long)m * 1536 + n] = f2bf((acc[mi][ni][r] + bn) * sc);
          }
      }
    }
  } else {
    float* D = (float*)outp + bz * obst;
    const float* R = resid + bz * rbst;
    #pragma unroll
    for (int mi = 0; mi < 4; mi++)
      #pragma unroll
      for (int r = 0; r < 4; r++) {
        int m = m0 + wm + mi * 16 + quad * 4 + r;
        float bm = bias[m];
        #pragma unroll
        for (int ni = 0; ni < 4; ni++) {
          int n = n0 + wn + ni * 16 + l15;
          long idx = (long)m * N + n;
          D[idx] = acc[mi][ni][r] + bm + R[idx];
        }
      }
  }
}

// ---------- flash attention (S^T formulation, async dbuf K/V, no-max softmax) ----------
// qkv: (B,T,1536) bf16, Q pre-scaled by 0.125*log2e; vt: (B,NH,64,T) bf16.
// Scores s = (q.k)/8 bounded -> p = exp2(s*log2e) without max-subtraction;
// l = sum p via ones-MFMA. P round-trips LDS in two 32-tk halves (4KB/wave),
// total LDS = 48KB -> 3 blocks/CU at natural VGPR (~108; 3 blocks need <=170).
// NOTE: no min-waves forcing — (256,3) capped VGPR at 84 and spilled ~1.2GB
// of scratch traffic to HBM (R5 post-mortem).
__global__ __launch_bounds__(256, 2) void attn(const u16* __restrict__ qkv,
                                               const u16* __restrict__ vt,
                                               u16* __restrict__ aout) {
  __shared__ __align__(16) u16 Ps[4][64 * 32];   // 16KB: per-wave 64 tq x 32 tk half
  __shared__ __align__(16) u16 Ks[2][64 * 64];   // 2x8KB
  __shared__ __align__(16) u16 Vs[2][64 * 64];   // 2x8KB
  const int tid = threadIdx.x, lane = tid & 63, wave = tid >> 6;
  const int l15 = lane & 15, quad = lane >> 4;
  const int sw = l15 & 7;                        // K/V row-swizzle key
  const int sw2 = l15 & 3;                       // P row-swizzle key (4 granules)
  const int b = blockIdx.y >> 3, h = blockIdx.y & 7;
  const int t0 = blockIdx.x * 256;
  const u16* qbase = qkv + (long)b * 2048 * 1536 + h * 192;
  const u16* vbase = vt + (long)(b * 8 + h) * 64 * 2048;
  u16* PsW = &Ps[wave][0];

  // Q fragments straight from global (A-layout: 16B/lane)
  short8 qf[4][2];
  #pragma unroll
  for (int tqi = 0; tqi < 4; tqi++)
    #pragma unroll
    for (int ks = 0; ks < 2; ks++)
      qf[tqi][ks] = ld8(qbase + (long)(t0 + wave * 64 + tqi * 16 + l15) * 1536 + ks * 32 + quad * 8);

  // ones A-fragment for l-sum MFMA (bf16 1.0 = 0x3F80)
  short8 ones;
  #pragma unroll
  for (int j = 0; j < 8; j++) ones[j] = (short)0x3F80;

  // staging source pointers: lane covers phys chunk p, reads logical chunk c = (p&7)^(row&7)
  const u16* kg[2]; const u16* vg[2]; int ldso[2];
  #pragma unroll
  for (int half = 0; half < 2; half++) {
    int p = half * 256 + wave * 64 + lane;
    int row = p >> 3, c = (p & 7) ^ (row & 7);
    kg[half] = qbase + (long)row * 1536 + 64 + c * 8;
    vg[half] = vbase + (long)row * 2048 + c * 8;
    ldso[half] = (half * 256 + wave * 64) * 8;
  }
  #pragma unroll
  for (int half = 0; half < 2; half++) {
    async_ld16(kg[half], &Ks[0][ldso[half]]);
    async_ld16(vg[half], &Vs[0][ldso[half]]);
  }

  floatx4 accO[4][4];   // [ci][tqi]: row=c, col=tq
  floatx4 lacc[4];      // [tqi]
  #pragma unroll
  for (int ci = 0; ci < 4; ci++)
    #pragma unroll
    for (int tqi = 0; tqi < 4; tqi++) accO[ci][tqi] = (floatx4){0.f, 0.f, 0.f, 0.f};
  #pragma unroll
  for (int tqi = 0; tqi < 4; tqi++) lacc[tqi] = (floatx4){0.f, 0.f, 0.f, 0.f};

  for (int it = 0; it < 32; it++) {
    const u16* kb = Ks[it & 1];
    const u16* vb = Vs[it & 1];
    __syncthreads();                     // publishes tile it; frees buffer it^1
    if (it < 31) {                       // prefetch tile it+1
      int s1 = (it + 1) * 64;
      u16* kn = Ks[(it & 1) ^ 1];
      u16* vn = Vs[(it & 1) ^ 1];
      #pragma unroll
      for (int half = 0; half < 2; half++) {
        async_ld16(kg[half] + (long)s1 * 1536, &kn[ldso[half]]);
        async_ld16(vg[half] + s1,              &vn[ldso[half]]);
      }
    }

    // S^T[tk][tq] = sum_c K[tk][c] * Q[tq][c]
    floatx4 sacc[4][4];   // [tki][tqi]
    #pragma unroll
    for (int i = 0; i < 4; i++)
      #pragma unroll
      for (int j = 0; j < 4; j++) sacc[i][j] = (floatx4){0.f, 0.f, 0.f, 0.f};
    #pragma unroll
    for (int ks = 0; ks < 2; ks++) {
      short8 kf[4];
      #pragma unroll
      for (int tki = 0; tki < 4; tki++)
        kf[tki] = ld8(&kb[((tki * 16 + l15) << 6) + (((ks * 4 + quad) ^ sw) << 3)]);
      #pragma unroll
      for (int tki = 0; tki < 4; tki++)
        #pragma unroll
        for (int tqi = 0; tqi < 4; tqi++)
          sacc[tki][tqi] = __builtin_amdgcn_mfma_f32_16x16x32_bf16(kf[tki], qf[tqi][ks], sacc[tki][tqi], 0, 0, 0);
    }

    // Two 32-tk halves: exp2+pack+write P half, then PV/l MFMAs on that half.
    #pragma unroll
    for (int ks = 0; ks < 2; ks++) {
      #pragma unroll
      for (int tqi = 0; tqi < 4; tqi++) {
        int prow = (tqi * 16 + l15) << 5;          // 32 u16 per row
        #pragma unroll
        for (int th = 0; th < 2; th++) {
          int tki = ks * 2 + th;
          float p0 = __builtin_amdgcn_exp2f(sacc[tki][tqi][0]);
          float p1 = __builtin_amdgcn_exp2f(sacc[tki][tqi][1]);
          float p2 = __builtin_amdgcn_exp2f(sacc[tki][tqi][2]);
          float p3 = __builtin_amdgcn_exp2f(sacc[tki][tqi][3]);
          union { u32 u[2]; float2 f; } pk;
          pk.u[0] = __builtin_amdgcn_perm(__float_as_uint(p1), __float_as_uint(p0), 0x07060302);
          pk.u[1] = __builtin_amdgcn_perm(__float_as_uint(p3), __float_as_uint(p2), 0x07060302);
          int c4 = th * 2 + (quad >> 1);           // 16B granule within row
          *reinterpret_cast<float2*>(
              &PsW[prow + (((c4 ^ sw2) << 3) | ((quad & 1) << 2))]) = pk.f;
        }
      }
      short8 vf[4], pf[4];
      #pragma unroll
      for (int ci = 0; ci < 4; ci++)
        vf[ci] = ld8(&vb[((ci * 16 + l15) << 6) + (((ks * 4 + quad) ^ sw) << 3)]);
      #pragma unroll
      for (int tqi = 0; tqi < 4; tqi++)
        pf[tqi] = ld8(&PsW[((tqi * 16 + l15) << 5) + ((quad ^ sw2) << 3)]);
      #pragma unroll
      for (int tqi = 0; tqi < 4; tqi++)
        lacc[tqi] = __builtin_amdgcn_mfma_f32_16x16x32_bf16(ones, pf[tqi], lacc[tqi], 0, 0, 0);
      #pragma unroll
      for (int ci = 0; ci < 4; ci++)
        #pragma unroll
        for (int tqi = 0; tqi < 4; tqi++)
          accO[ci][tqi] = __builtin_amdgcn_mfma_f32_16x16x32_bf16(vf[ci], pf[tqi], accO[ci][tqi], 0, 0, 0);
    }
  }

  // epilogue: normalize, write a (B,T,C) bf16; lane holds 4 consecutive c
  u16* ob = aout + ((long)b * 2048 + t0 + wave * 64) * 512 + h * 64;
  #pragma unroll
  for (int tqi = 0; tqi < 4; tqi++) {
    float invl = 1.f / lacc[tqi][0];
    #pragma unroll
    for (int ci = 0; ci < 4; ci++) {
      union { u16 u[4]; float2 f; } pk;
      #pragma unroll
      for (int r = 0; r < 4; r++) pk.u[r] = f2bf(accO[ci][tqi][r] * invl);
      *reinterpret_cast<float2*>(ob + (long)(tqi * 16 + l15) * 512 + ci * 16 + quad * 4) = pk.f;
    }
  }
}

// ---------- launch ----------
extern "C" void kernel_launch(void* const* d_in, const int* in_sizes, int n_in,
                              void* d_out, int out_size, void* d_ws, size_t ws_size,
                              hipStream_t stream) {
  const float* x   = (const float*)d_in[0];
  const float* g1  = (const float*)d_in[1];
  const float* be1 = (const float*)d_in[2];
  const float* wq  = (const float*)d_in[3];
  const float* bq  = (const float*)d_in[4];
  const float* g2  = (const float*)d_in[5];
  const float* be2 = (const float*)d_in[6];
  const float* wp  = (const float*)d_in[7];
  const float* bp  = (const float*)d_in[8];

  char* ws = (char*)d_ws;
  u16*   xn   = (u16*)ws;                        // 16.8 MB, dead after gemm1
  u16*   a    = (u16*)ws;                        // bf16 attn out, alias xn (disjoint lifetime)
  u16*   qkvb = (u16*)(ws + 33554432);           // 50.3 MB (q/k live, v-holes unused)
  u16*   hn   = (u16*)(ws + 83886080);           // 16.8 MB, gn2 -> gemm2
  u16*   vtb  = hn;                              // alias: Vt lifetime gemm1 -> attn
  u16*   wqb  = (u16*)(ws + 100663296);          // 1.6 MB
  u16*   wpb  = (u16*)(ws + 102236160);          // 0.5 MB

  cast_both<<<1024, 256, 0, stream>>>(wq, wqb, wp, wpb);
  gn_ct<<<256, 1024, 0, stream>>>(x, g1, be1, xn);
  // qkv[b][t][o] = sum_c xn[b][t][c] * Wq[o][c] + bq[o]  (+ q-scale, v->Vt)
  gemm_tn<1><<<dim3(12, 16, 8), 256, 0, stream>>>(
      xn, (long)2048 * 512, wqb, 0, bq, nullptr, 0, qkvb, (long)2048 * 1536, vtb, 512);
  attn<<<dim3(8, 64), 256, 0, stream>>>(qkvb, vtb, a);
  gn_tc<<<256, 1024, 0, stream>>>(a, g2, be2, hn);
  // out[b][o][t] = x[b][o][t] + bp[o] + sum_c Wp[o][c] * hn[b][t][c]
  gemm_tn<0><<<dim3(16, 4, 8), 256, 0, stream>>>(
      wpb, 0, hn, (long)2048 * 512, bp, x, (long)512 * 2048, d_out, (long)512 * 2048, nullptr, 512);
}

// Round 7
// 273.588 us; speedup vs baseline: 1.7568x; 1.0527x over previous
//
#include <hip/hip_runtime.h>

typedef unsigned short u16;
typedef unsigned int   u32;
typedef __attribute__((ext_vector_type(8))) short short8;
typedef __attribute__((ext_vector_type(4))) float floatx4;

// ---------- helpers ----------
__device__ inline u16 f2bf(float x) {
  union { float f; unsigned u; } v; v.f = x;
  unsigned r = v.u + 0x7FFFu + ((v.u >> 16) & 1u);   // RNE
  return (u16)(r >> 16);
}
__device__ inline float bf2f(short s) {
  union { u32 u; float f; } v; v.u = ((u32)(u16)s) << 16; return v.f;
}
__device__ inline short8 ld8(const u16* p) {
  return *reinterpret_cast<const short8*>(p);
}
// async global->LDS DMA, 16B per lane; lds dest = wave-uniform base + lane*16
__device__ inline void async_ld16(const u16* g, u16* l) {
  unsigned loff = (unsigned)(unsigned long long)(void*)l;
  __builtin_amdgcn_global_load_lds(reinterpret_cast<const unsigned*>(g),
      reinterpret_cast<__attribute__((address_space(3))) unsigned*>(loff), 16, 0, 0);
}

// ---------- fused GroupNorm-1 + weight casts ----------
// blocks 0..255: GN over x (B,C,T) fp32 -> xn (B,T,C) bf16, single global read:
//   group (16ch x 2048t) staged as bf16 in exactly 64KB LDS; stats scratch
//   overlaps tile[0..63] (c=0,t<64), those pass-2 reads fall back to global.
// blocks 256..511: cast wq (786432 f) + wp (262144 f) fp32 -> bf16.
__global__ __launch_bounds__(1024) void gncast(const float* __restrict__ x,
                                               const float* __restrict__ gamma,
                                               const float* __restrict__ beta,
                                               u16* __restrict__ xn,
                                               const float* __restrict__ wq,
                                               u16* __restrict__ wqb,
                                               const float* __restrict__ wp,
                                               u16* __restrict__ wpb) {
  __shared__ u16 tile[16 * 2048];                 // 64KB exact
  float* stats = (float*)tile;                    // overlaps first 128B
  const int tid = threadIdx.x;
  if (blockIdx.x >= 256) {                        // ---- cast part ----
    int i = (blockIdx.x - 256) * 1024 + tid;      // float4 index
    const float* src; u16* dst; int j;
    if (i < 196608) { src = wq; dst = wqb; j = i; }
    else            { src = wp; dst = wpb; j = i - 196608; }
    float4 v = reinterpret_cast<const float4*>(src)[j];
    union { u16 u[4]; float2 f; } w;
    w.u[0] = f2bf(v.x); w.u[1] = f2bf(v.y); w.u[2] = f2bf(v.z); w.u[3] = f2bf(v.w);
    reinterpret_cast<float2*>(dst)[j] = w.f;
    return;
  }
  // ---- GN part ----
  int b = blockIdx.x >> 5, g = blockIdx.x & 31;
  const float* base = x + ((long)b * 512 + g * 16) * 2048;
  float s = 0.f, ss = 0.f;
  for (int i = tid; i < 8192; i += 1024) {        // pass 1: read + stage bf16
    float4 v = reinterpret_cast<const float4*>(base)[i];
    s  += v.x + v.y + v.z + v.w;
    ss += v.x * v.x + v.y * v.y + v.z * v.z + v.w * v.w;
    int c = i >> 9, t4 = (i & 511) * 4;
    union { u16 u[4]; float2 f; } w;
    w.u[0] = f2bf(v.x); w.u[1] = f2bf(v.y); w.u[2] = f2bf(v.z); w.u[3] = f2bf(v.w);
    *reinterpret_cast<float2*>(&tile[c * 2048 + t4]) = w.f;
  }
  #pragma unroll
  for (int d = 1; d < 64; d <<= 1) { s += __shfl_xor(s, d); ss += __shfl_xor(ss, d); }
  __syncthreads();                                 // tile writes done
  int wave = tid >> 6, lane = tid & 63;
  if (lane == 0) { stats[wave] = s; stats[wave + 16] = ss; }
  __syncthreads();
  s = 0.f; ss = 0.f;
  #pragma unroll
  for (int w = 0; w < 16; w++) { s += stats[w]; ss += stats[w + 16]; }
  float mean = s * (1.f / 32768.f);
  float var  = ss * (1.f / 32768.f) - mean * mean;
  float rstd = rsqrtf(var + 1e-5f);
  float ga[16], be[16];
  #pragma unroll
  for (int c = 0; c < 16; c++) {
    float gm = gamma[g * 16 + c];
    ga[c] = gm * rstd;
    be[c] = beta[g * 16 + c] - mean * rstd * gm;
  }
  u16* ob = xn + (long)b * 2048 * 512 + g * 16;
  #pragma unroll
  for (int tt = 0; tt < 2; tt++) {                 // pass 2: LDS -> xn
    int t = tid * 2 + tt;
    union { u16 u[8]; float4 f; } w0, w1;
    #pragma unroll
    for (int c = 0; c < 16; c++) {
      float f;
      if (c == 0 && t < 64) f = base[t];           // stats-overlap fallback
      else                  f = bf2f((short)tile[c * 2048 + t]);
      u16 o = f2bf(f * ga[c] + be[c]);
      if (c < 8) w0.u[c] = o; else w1.u[c - 8] = o;
    }
    u16* dst = ob + (long)t * 512;
    *reinterpret_cast<float4*>(dst)     = w0.f;
    *reinterpret_cast<float4*>(dst + 8) = w1.f;
  }
}

// ---------- GroupNorm 2: a (B,T,C) bf16 -> hn (B,T,C) bf16 ----------
__global__ __launch_bounds__(1024) void gn_tc(const u16* __restrict__ a,
                                              const float* __restrict__ gamma,
                                              const float* __restrict__ beta,
                                              u16* __restrict__ hn) {
  int b = blockIdx.x >> 5, g = blockIdx.x & 31;
  const u16* base = a + (long)b * 2048 * 512 + g * 16;
  float s = 0.f, ss = 0.f;
  for (int t = threadIdx.x; t < 2048; t += 1024) {
    const u16* p = base + (long)t * 512;
    short8 v0 = ld8(p), v1 = ld8(p + 8);
    #pragma unroll
    for (int j = 0; j < 8; j++) {
      float f0 = bf2f(v0[j]), f1 = bf2f(v1[j]);
      s += f0 + f1; ss += f0 * f0 + f1 * f1;
    }
  }
  #pragma unroll
  for (int d = 1; d < 64; d <<= 1) { s += __shfl_xor(s, d); ss += __shfl_xor(ss, d); }
  __shared__ float red[32];
  int wave = threadIdx.x >> 6, lane = threadIdx.x & 63;
  if (lane == 0) { red[wave] = s; red[wave + 16] = ss; }
  __syncthreads();
  s = 0.f; ss = 0.f;
  #pragma unroll
  for (int w = 0; w < 16; w++) { s += red[w]; ss += red[w + 16]; }
  float mean = s * (1.f / 32768.f);
  float var  = ss * (1.f / 32768.f) - mean * mean;
  float rstd = rsqrtf(var + 1e-5f);
  float ga[16], be[16];
  #pragma unroll
  for (int c = 0; c < 16; c++) {
    float gm = gamma[g * 16 + c];
    ga[c] = gm * rstd;
    be[c] = beta[g * 16 + c] - mean * rstd * gm;
  }
  u16* ob = hn + (long)b * 2048 * 512 + g * 16;
  for (int t = threadIdx.x; t < 2048; t += 1024) {
    const u16* p = base + (long)t * 512;
    short8 v0 = ld8(p), v1 = ld8(p + 8);
    union { u16 u[8]; float4 f; } w0, w1;
    #pragma unroll
    for (int c = 0; c < 8; c++)  w0.u[c] = f2bf(bf2f(v0[c]) * ga[c] + be[c]);
    #pragma unroll
    for (int c = 0; c < 8; c++)  w1.u[c] = f2bf(bf2f(v1[c]) * ga[c + 8] + be[c + 8]);
    u16* dst = ob + (long)t * 512;
    *reinterpret_cast<float4*>(dst)     = w0.f;
    *reinterpret_cast<float4*>(dst + 8) = w1.f;
  }
}

// ---------- unified TN GEMM: D[m][n] = sum_k A[m][k] * Bt[n][k] ----------
// Double-buffered async K-loop: one barrier/iter, prefetch k+1 during compute k.
template<int QKV>
__global__ __launch_bounds__(256) void gemm_tn(
    const u16* __restrict__ A, long abst,
    const u16* __restrict__ Bt, long bbst,
    const float* __restrict__ bias,
    const float* __restrict__ resid, long rbst,
    void* __restrict__ outp, long obst,
    u16* __restrict__ vtp, int K) {
  __shared__ __align__(16) u16 As[2][128 * 32];
  __shared__ __align__(16) u16 Bs[2][128 * 32];
  const int tid = threadIdx.x;
  const int m0 = blockIdx.y * 128, n0 = blockIdx.x * 128;
  const int N = gridDim.x * 128;
  const long bz = blockIdx.z;
  const u16* Ab = A + bz * abst + (long)m0 * K;
  const u16* Bb = Bt + bz * bbst + (long)n0 * K;
  const int lane = tid & 63, wave = tid >> 6;
  const int wm = (wave & 1) * 64, wn = (wave >> 1) * 64;
  const int l15 = lane & 15, quad = lane >> 4;
  const u16* ag[2]; const u16* bg[2];
  const int ldso = wave * 512;
  #pragma unroll
  for (int half = 0; half < 2; half++) {
    int r = half * 64 + (tid >> 2);
    ag[half] = Ab + (long)r * K + (tid & 3) * 8;
    bg[half] = Bb + (long)r * K + (tid & 3) * 8;
  }

  floatx4 acc[4][4];
  #pragma unroll
  for (int i = 0; i < 4; i++)
    #pragma unroll
    for (int j = 0; j < 4; j++) acc[i][j] = (floatx4){0.f, 0.f, 0.f, 0.f};

  #pragma unroll
  for (int half = 0; half < 2; half++) {
    async_ld16(ag[half], &As[0][half * 2048 + ldso]);
    async_ld16(bg[half], &Bs[0][half * 2048 + ldso]);
  }
  const int nk = K >> 5;
  for (int ki = 0; ki < nk; ki++) {
    __syncthreads();
    if (ki + 1 < nk) {
      int k1 = (ki + 1) << 5, bsel = (ki + 1) & 1;
      #pragma unroll
      for (int half = 0; half < 2; half++) {
        async_ld16(ag[half] + k1, &As[bsel][half * 2048 + ldso]);
        async_ld16(bg[half] + k1, &Bs[bsel][half * 2048 + ldso]);
      }
    }
    const u16* as = As[ki & 1]; const u16* bs = Bs[ki & 1];
    short8 af[4], bfr[4];
    #pragma unroll
    for (int i = 0; i < 4; i++) af[i]  = ld8(&as[(wm + i * 16 + l15) * 32 + quad * 8]);
    #pragma unroll
    for (int i = 0; i < 4; i++) bfr[i] = ld8(&bs[(wn + i * 16 + l15) * 32 + quad * 8]);
    #pragma unroll
    for (int mi = 0; mi < 4; mi++)
      #pragma unroll
      for (int ni = 0; ni < 4; ni++)
        acc[mi][ni] = __builtin_amdgcn_mfma_f32_16x16x32_bf16(af[mi], bfr[ni], acc[mi][ni], 0, 0, 0);
  }

  if (QKV) {
    u16* D  = (u16*)outp + bz * obst;
    u16* VT = vtp + bz * (8L * 64 * 2048);
    #pragma unroll
    for (int ni = 0; ni < 4; ni++) {
      int nb = n0 + wn + ni * 16;
      int region = (nb >> 6) % 3;              // 0=q, 1=k, 2=v
      int n = nb + l15;
      float bn = bias[n];
      if (region == 2) {
        int hh = n / 192, c = (n % 192) - 128;
        u16* vrow = VT + ((long)hh * 64 + c) * 2048 + m0 + wm;
        #pragma unroll
        for (int mi = 0; mi < 4; mi++) {
          union { u16 u[4]; float2 f; } pk;
          #pragma unroll
          for (int r = 0; r < 4; r++) pk.u[r] = f2bf(acc[mi][ni][r] + bn);
          *reinterpret_cast<float2*>(vrow + mi * 16 + quad * 4) = pk.f;
        }
      } else {
        float sc = (region == 0) ? 0.180336880f : 1.f;   // 0.125 * log2(e)
        #pragma unroll
        for (int mi = 0; mi < 4; mi++)
          #pragma unroll
          for (int r = 0; r < 4; r++) {
            int m = m0 + wm + mi * 16 + quad * 4 + r;
            D[(long)m * 1536 + n] = f2bf((acc[mi][ni][r] + bn) * sc);
          }
      }
    }
  } else {
    float* D = (float*)outp + bz * obst;
    const float* R = resid + bz * rbst;
    #pragma unroll
    for (int mi = 0; mi < 4; mi++)
      #pragma unroll
      for (int r = 0; r < 4; r++) {
        int m = m0 + wm + mi * 16 + quad * 4 + r;
        float bm = bias[m];
        #pragma unroll
        for (int ni = 0; ni < 4; ni++) {
          int n = n0 + wn + ni * 16 + l15;
          long idx = (long)m * N + n;
          D[idx] = acc[mi][ni][r] + bm + R[idx];
        }
      }
  }
}

// ---------- flash attention (R4 config + XCD-swizzled 1D grid) ----------
// qkv: (B,T,1536) bf16, Q pre-scaled by 0.125*log2e; vt: (B,NH,64,T) bf16.
// No-max softmax (bounded scores), l via ones-MFMA, full-width P (128B rows).
// Grid 512 1D: bh = id&63, tqb = id>>6 -> the 8 tq-blocks of one (b,h) land on
// one XCD if dispatch is id%8-round-robin (K/V L2 locality; perf-only).
__global__ __launch_bounds__(256, 2) void attn(const u16* __restrict__ qkv,
                                               const u16* __restrict__ vt,
                                               u16* __restrict__ aout) {
  __shared__ __align__(16) u16 Ps[256 * 64];     // 32KB, P (wave-private rows, swizzled)
  __shared__ __align__(16) u16 Ks[2][64 * 64];   // 2x8KB
  __shared__ __align__(16) u16 Vs[2][64 * 64];   // 2x8KB
  const int tid = threadIdx.x, lane = tid & 63, wave = tid >> 6;
  const int l15 = lane & 15, quad = lane >> 4;
  const int sw = l15 & 7;                        // row-swizzle key
  const int bh = blockIdx.x & 63;
  const int b = bh >> 3, h = bh & 7;
  const int t0 = (blockIdx.x >> 6) * 256;
  const u16* qbase = qkv + (long)b * 2048 * 1536 + h * 192;
  const u16* vbase = vt + (long)(b * 8 + h) * 64 * 2048;

  // Q fragments straight from global (A-layout: 16B/lane)
  short8 qf[4][2];
  #pragma unroll
  for (int tqi = 0; tqi < 4; tqi++)
    #pragma unroll
    for (int ks = 0; ks < 2; ks++)
      qf[tqi][ks] = ld8(qbase + (long)(t0 + wave * 64 + tqi * 16 + l15) * 1536 + ks * 32 + quad * 8);

  // ones A-fragment for l-sum MFMA (bf16 1.0 = 0x3F80)
  short8 ones;
  #pragma unroll
  for (int j = 0; j < 8; j++) ones[j] = (short)0x3F80;

  // staging source pointers: lane covers phys chunk p, reads logical chunk c = (p&7)^(row&7)
  const u16* kg[2]; const u16* vg[2]; int ldso[2];
  #pragma unroll
  for (int half = 0; half < 2; half++) {
    int p = half * 256 + wave * 64 + lane;
    int row = p >> 3, c = (p & 7) ^ (row & 7);
    kg[half] = qbase + (long)row * 1536 + 64 + c * 8;
    vg[half] = vbase + (long)row * 2048 + c * 8;
    ldso[half] = (half * 256 + wave * 64) * 8;
  }
  #pragma unroll
  for (int half = 0; half < 2; half++) {
    async_ld16(kg[half], &Ks[0][ldso[half]]);
    async_ld16(vg[half], &Vs[0][ldso[half]]);
  }

  floatx4 accO[4][4];   // [ci][tqi]: row=c, col=tq
  floatx4 lacc[4];      // [tqi]
  #pragma unroll
  for (int ci = 0; ci < 4; ci++)
    #pragma unroll
    for (int tqi = 0; tqi < 4; tqi++) accO[ci][tqi] = (floatx4){0.f, 0.f, 0.f, 0.f};
  #pragma unroll
  for (int tqi = 0; tqi < 4; tqi++) lacc[tqi] = (floatx4){0.f, 0.f, 0.f, 0.f};

  for (int it = 0; it < 32; it++) {
    const u16* kb = Ks[it & 1];
    const u16* vb = Vs[it & 1];
    __syncthreads();                     // publishes tile it; frees buffer it^1
    if (it < 31) {                       // prefetch tile it+1
      int s1 = (it + 1) * 64;
      u16* kn = Ks[(it & 1) ^ 1];
      u16* vn = Vs[(it & 1) ^ 1];
      #pragma unroll
      for (int half = 0; half < 2; half++) {
        async_ld16(kg[half] + (long)s1 * 1536, &kn[ldso[half]]);
        async_ld16(vg[half] + s1,              &vn[ldso[half]]);
      }
    }

    // S^T[tk][tq] = sum_c K[tk][c] * Q[tq][c]
    floatx4 sacc[4][4];   // [tki][tqi]
    #pragma unroll
    for (int i = 0; i < 4; i++)
      #pragma unroll
      for (int j = 0; j < 4; j++) sacc[i][j] = (floatx4){0.f, 0.f, 0.f, 0.f};
    #pragma unroll
    for (int ks = 0; ks < 2; ks++) {
      short8 kf[4];
      #pragma unroll
      for (int tki = 0; tki < 4; tki++)
        kf[tki] = ld8(&kb[((tki * 16 + l15) << 6) + (((ks * 4 + quad) ^ sw) << 3)]);
      #pragma unroll
      for (int tki = 0; tki < 4; tki++)
        #pragma unroll
        for (int tqi = 0; tqi < 4; tqi++)
          sacc[tki][tqi] = __builtin_amdgcn_mfma_f32_16x16x32_bf16(kf[tki], qf[tqi][ks], sacc[tki][tqi], 0, 0, 0);
    }

    // p = exp2(s) (no max-sub; bounded domain), pack & write P
    #pragma unroll
    for (int tqi = 0; tqi < 4; tqi++) {
      int prow = (wave * 64 + tqi * 16 + l15) << 6;
      #pragma unroll
      for (int tki = 0; tki < 4; tki++) {
        float p0 = __builtin_amdgcn_exp2f(sacc[tki][tqi][0]);
        float p1 = __builtin_amdgcn_exp2f(sacc[tki][tqi][1]);
        float p2 = __builtin_amdgcn_exp2f(sacc[tki][tqi][2]);
        float p3 = __builtin_amdgcn_exp2f(sacc[tki][tqi][3]);
        union { u32 u[2]; float2 f; } pk;
        pk.u[0] = __builtin_amdgcn_perm(__float_as_uint(p1), __float_as_uint(p0), 0x07060302);
        pk.u[1] = __builtin_amdgcn_perm(__float_as_uint(p3), __float_as_uint(p2), 0x07060302);
        int c16 = tki * 2 + (quad >> 1);
        *reinterpret_cast<float2*>(
            &Ps[prow + ((c16 ^ sw) << 3) + ((quad & 1) << 2)]) = pk.f;
      }
    }

    // O^T[c][tq] += sum_tk V^T[c][tk] * P[tq][tk]; l[tq] += sum_tk P
    #pragma unroll
    for (int ks = 0; ks < 2; ks++) {
      short8 vf[4], pf[4];
      #pragma unroll
      for (int ci = 0; ci < 4; ci++)
        vf[ci] = ld8(&vb[((ci * 16 + l15) << 6) + (((ks * 4 + quad) ^ sw) << 3)]);
      #pragma unroll
      for (int tqi = 0; tqi < 4; tqi++)
        pf[tqi] = ld8(&Ps[((wave * 64 + tqi * 16 + l15) << 6) + (((ks * 4 + quad) ^ sw) << 3)]);
      #pragma unroll
      for (int tqi = 0; tqi < 4; tqi++)
        lacc[tqi] = __builtin_amdgcn_mfma_f32_16x16x32_bf16(ones, pf[tqi], lacc[tqi], 0, 0, 0);
      #pragma unroll
      for (int ci = 0; ci < 4; ci++)
        #pragma unroll
        for (int tqi = 0; tqi < 4; tqi++)
          accO[ci][tqi] = __builtin_amdgcn_mfma_f32_16x16x32_bf16(vf[ci], pf[tqi], accO[ci][tqi], 0, 0, 0);
    }
  }

  // epilogue: normalize, write a (B,T,C) bf16; lane holds 4 consecutive c
  u16* ob = aout + ((long)b * 2048 + t0 + wave * 64) * 512 + h * 64;
  #pragma unroll
  for (int tqi = 0; tqi < 4; tqi++) {
    float invl = 1.f / lacc[tqi][0];
    #pragma unroll
    for (int ci = 0; ci < 4; ci++) {
      union { u16 u[4]; float2 f; } pk;
      #pragma unroll
      for (int r = 0; r < 4; r++) pk.u[r] = f2bf(accO[ci][tqi][r] * invl);
      *reinterpret_cast<float2*>(ob + (long)(tqi * 16 + l15) * 512 + ci * 16 + quad * 4) = pk.f;
    }
  }
}

// ---------- launch ----------
extern "C" void kernel_launch(void* const* d_in, const int* in_sizes, int n_in,
                              void* d_out, int out_size, void* d_ws, size_t ws_size,
                              hipStream_t stream) {
  const float* x   = (const float*)d_in[0];
  const float* g1  = (const float*)d_in[1];
  const float* be1 = (const float*)d_in[2];
  const float* wq  = (const float*)d_in[3];
  const float* bq  = (const float*)d_in[4];
  const float* g2  = (const float*)d_in[5];
  const float* be2 = (const float*)d_in[6];
  const float* wp  = (const float*)d_in[7];
  const float* bp  = (const float*)d_in[8];

  char* ws = (char*)d_ws;
  u16*   xn   = (u16*)ws;                        // 16.8 MB, dead after gemm1
  u16*   a    = (u16*)ws;                        // bf16 attn out, alias xn (disjoint lifetime)
  u16*   qkvb = (u16*)(ws + 33554432);           // 50.3 MB (q/k live, v-holes unused)
  u16*   hn   = (u16*)(ws + 83886080);           // 16.8 MB, gn2 -> gemm2
  u16*   vtb  = hn;                              // alias: Vt lifetime gemm1 -> attn
  u16*   wqb  = (u16*)(ws + 100663296);          // 1.6 MB
  u16*   wpb  = (u16*)(ws + 102236160);          // 0.5 MB

  gncast<<<512, 1024, 0, stream>>>(x, g1, be1, xn, wq, wqb, wp, wpb);
  // qkv[b][t][o] = sum_c xn[b][t][c] * Wq[o][c] + bq[o]  (+ q-scale, v->Vt)
  gemm_tn<1><<<dim3(12, 16, 8), 256, 0, stream>>>(
      xn, (long)2048 * 512, wqb, 0, bq, nullptr, 0, qkvb, (long)2048 * 1536, vtb, 512);
  attn<<<512, 256, 0, stream>>>(qkvb, vtb, a);
  gn_tc<<<256, 1024, 0, stream>>>(a, g2, be2, hn);
  // out[b][o][t] = x[b][o][t] + bp[o] + sum_c Wp[o][c] * hn[b][t][c]
  gemm_tn<0><<<dim3(16, 4, 8), 256, 0, stream>>>(
      wpb, 0, hn, (long)2048 * 512, bp, x, (long)512 * 2048, d_out, (long)512 * 2048, nullptr, 512);
}